// Round 8
// baseline (684.210 us; speedup 1.0000x reference)
//
#include <hip/hip_runtime.h>
#include <hip/hip_bf16.h>
#include <math.h>

#define S_LEN 2048
#define BATCH 2
#define HID 1024
#define NHEAD 16
#define HDIM 64
#define NTOK (S_LEN*BATCH)   // 4096

typedef __bf16 bf16;
typedef __bf16 bf16x4 __attribute__((ext_vector_type(4)));
typedef __bf16 bf16x8 __attribute__((ext_vector_type(8)));
typedef float f32x4 __attribute__((ext_vector_type(4)));

typedef const __attribute__((address_space(1))) unsigned int* gptr_t;
typedef __attribute__((address_space(3))) unsigned int* lptr_t;

__device__ __forceinline__ void gload16(const void* g, void* l) {
    __builtin_amdgcn_global_load_lds((gptr_t)g, (lptr_t)l, 16, 0, 0);
}

// ---------------- fp32 -> bf16 convert (8 elems/thread) ----------------
__global__ void cvt_f32_bf16(const float* __restrict__ src, bf16* __restrict__ dst, int n) {
    int i = (blockIdx.x * blockDim.x + threadIdx.x) * 8;
    if (i >= n) return;
    const float4* s = (const float4*)(src + i);
    float4 a = s[0], b = s[1];
    bf16x8 o;
    o[0] = (bf16)a.x; o[1] = (bf16)a.y; o[2] = (bf16)a.z; o[3] = (bf16)a.w;
    o[4] = (bf16)b.x; o[5] = (bf16)b.y; o[6] = (bf16)b.z; o[7] = (bf16)b.w;
    *(bf16x8*)(dst + i) = o;
}

// ---------------- GEMM: C[M][N] = A[M][K] * B[N][K]^T ----------------
#define BM 128
#define BN 128
#define BK 32

__global__ __launch_bounds__(256) void gemm_bt(
    const bf16* __restrict__ A, const bf16* __restrict__ B,
    int M, int N, int K, int mode,
    const float* __restrict__ bq, const float* __restrict__ bk,
    const float* __restrict__ bv, const float* __restrict__ bo,
    bf16* __restrict__ qh, bf16* __restrict__ kh, bf16* __restrict__ vT,
    float* __restrict__ outp)
{
    __shared__ __align__(16) bf16 As[BM * BK];
    __shared__ __align__(16) bf16 Bs[BN * BK];
    const int tid = threadIdx.x;
    const int lane = tid & 63, wv = tid >> 6;
    const int g = lane >> 4, l15 = lane & 15;
    const int wr = wv >> 1, wc = wv & 1;
    const int bm = blockIdx.y * BM, bn = blockIdx.x * BN;

    f32x4 zero4 = {0.f, 0.f, 0.f, 0.f};
    f32x4 acc[4][4];
#pragma unroll
    for (int mi = 0; mi < 4; mi++)
#pragma unroll
        for (int ni = 0; ni < 4; ni++) acc[mi][ni] = zero4;

    const int r0 = wv * 32 + (lane >> 2);
    const int c0 = (lane & 3) * 8;
    const bf16* Ag0 = A + (size_t)(bm + r0) * K + c0;
    const bf16* Ag1 = Ag0 + (size_t)16 * K;
    const bf16* Bg0 = B + (size_t)(bn + r0) * K + c0;
    const bf16* Bg1 = Bg0 + (size_t)16 * K;
    bf16* AsW = &As[(wv * 32) * BK];
    bf16* BsW = &Bs[(wv * 32) * BK];

    for (int k0 = 0; k0 < K; k0 += BK) {
        gload16(Ag0 + k0, AsW);
        gload16(Ag1 + k0, AsW + 16 * BK);
        gload16(Bg0 + k0, BsW);
        gload16(Bg1 + k0, BsW + 16 * BK);
        __syncthreads();

        bf16x8 aF[4], bF[4];
#pragma unroll
        for (int mi = 0; mi < 4; mi++)
            aF[mi] = *(const bf16x8*)&As[(wr * 64 + mi * 16 + l15) * BK + g * 8];
#pragma unroll
        for (int ni = 0; ni < 4; ni++)
            bF[ni] = *(const bf16x8*)&Bs[(wc * 64 + ni * 16 + l15) * BK + g * 8];
#pragma unroll
        for (int mi = 0; mi < 4; mi++)
#pragma unroll
            for (int ni = 0; ni < 4; ni++)
                acc[mi][ni] = __builtin_amdgcn_mfma_f32_16x16x32_bf16(
                    aF[mi], bF[ni], acc[mi][ni], 0, 0, 0);
        __syncthreads();
    }

    if (mode == 0) {
#pragma unroll
        for (int ni = 0; ni < 4; ni++) {
            int n = bn + wc * 64 + ni * 16 + l15;       // 0..3071
            int which = n >> 10;                         // 0=q 1=k 2=v
            int c = n & 1023;
            int nh = c >> 6, d = c & 63;
            const float* bias_p = (which == 0) ? bq : (which == 1) ? bk : bv;
            float bias = bias_p[c];
            float scl = (which == 0) ? 0.125f : 1.0f;
#pragma unroll
            for (int mi = 0; mi < 4; mi++) {
#pragma unroll
                for (int r = 0; r < 4; r++) {
                    int m = bm + wr * 64 + mi * 16 + g * 4 + r;  // token
                    int s = m >> 1, b = m & 1;
                    int head = b * NHEAD + nh;
                    bf16 val = (bf16)((acc[mi][ni][r] + bias) * scl);
                    if (which == 2)
                        vT[((size_t)(head * HDIM + d)) * S_LEN + s] = val;
                    else {
                        bf16* dst = (which == 0) ? qh : kh;
                        dst[((size_t)(head * S_LEN + s)) * HDIM + d] = val;
                    }
                }
            }
        }
    } else {
#pragma unroll
        for (int ni = 0; ni < 4; ni++) {
            int n = bn + wc * 64 + ni * 16 + l15;
            float bias = bo[n];
#pragma unroll
            for (int mi = 0; mi < 4; mi++) {
#pragma unroll
                for (int r = 0; r < 4; r++) {
                    int m = bm + wr * 64 + mi * 16 + g * 4 + r;
                    outp[(size_t)m * HID + n] = acc[mi][ni][r] + bias;
                }
            }
        }
    }
}

// ---------------- flash attention: split-K over the key range ----------------
// grid 2048 blocks x 4 waves. Block = one 16-row q-tile of one head.
// wave wv = b*2 + h: batch b, kv-half h (keys [h*1024, h*1024+1024)), 16 iters of 64.
// Mask tile [16 q][64 k] fp32 per half, shared by the two b-waves, double-buffered,
// DMA'd at iter top (flight = full iter), XOR-chunk swizzle (inverse on DMA src).
// End: (h=1) publishes (m,l,O) via LDS; (h=0) does the exact online-softmax merge.
__global__ __launch_bounds__(256, 6) void attn(
    const bf16* __restrict__ q, const bf16* __restrict__ kh_, const bf16* __restrict__ vT,
    const float* __restrict__ amask,   // [16][2048][2048]
    const float* __restrict__ kmask,   // [32][2048]
    bf16* __restrict__ ctx)            // [4096][1024]
{
    __shared__ __align__(16) char SMEM[16384 + 4 * 16 * 72 * 2];
    float* MT = (float*)SMEM;                       // [2 buf][2 h][16 rows][64] f32
    bf16 (*P)[16][72] = (bf16(*)[16][72])(SMEM + 16384);

    const int tid = threadIdx.x, lane = tid & 63, wv = tid >> 6;
    const int g = lane >> 4, l15 = lane & 15;
    const int b = wv >> 1, h = wv & 1;

    // XCD swizzle: 2048 blocks, XCD x owns heads {2x, 2x+1} -> K/V L2-resident
    const int hw = blockIdx.y * 128 + blockIdx.x;    // grid (128, 16)
    const int vid = (hw & 7) * 256 + (hw >> 3);
    const int nh = vid >> 7;
    const int qt = vid & 127;                        // q-tile (16 rows)
    const int q0 = qt * 16;
    const int n = b * NHEAD + nh;

    // Q fragments (B-operand of swapped QK^T)
    const bf16* qrow = q + ((size_t)(n * S_LEN + q0 + l15)) * HDIM;
    bf16x8 bQ0 = *(const bf16x8*)(qrow + g * 8);
    bf16x8 bQ1 = *(const bf16x8*)(qrow + 32 + g * 8);

    // mask DMA (waves 0,1 only; wave wv stages half h=wv).
    // tile layout [16 rows][16 chunks f32x4]; logical chunk c of row r at phys c^(r&7).
    // instr j covers rows 4j..4j+3: lane -> row = 4j+(lane>>4), phys chunk = lane&15.
    int mrow0 = lane >> 4;
    const float* msrcJ[4];
#pragma unroll
    for (int j = 0; j < 4; j++) {
        int row = 4 * j + mrow0;
        int chunk = (lane & 15) ^ (row & 7);
        msrcJ[j] = amask + ((size_t)nh * S_LEN + q0 + row) * S_LEN + wv * 1024 + chunk * 4;
    }

    f32x4 zero4 = {0.f, 0.f, 0.f, 0.f};
    f32x4 O[4];
#pragma unroll
    for (int t = 0; t < 4; t++) O[t] = zero4;
    float mrun = -1e30f, lrun = 0.f;                 // per-lane row q = l15

    const int kk_base = h * 1024;
    const bf16* kbase = kh_ + ((size_t)n * S_LEN + kk_base + l15) * HDIM + g * 8;
    const bf16* vbase = vT + ((size_t)n * HDIM + l15) * S_LEN + kk_base + g * 8;
    const float* kmb = kmask + (size_t)n * S_LEN + kk_base + 4 * g;

    // prologue: stage tile 0 for both halves
    if (wv < 2) {
#pragma unroll
        for (int j = 0; j < 4; j++)
            gload16(msrcJ[j], MT + wv * 1024 + j * 256);
    }
    __syncthreads();

#pragma unroll 1
    for (int it = 0; it < 16; ++it) {
        const int tt = it * 64;                      // local key offset within half
        const int cur = it & 1;
        float* tile = MT + (cur * 2 + h) * 1024;
        // 1. DMA next tiles (full-iteration flight, lands at end-of-iter barrier)
        if (it < 15 && wv < 2) {
            float* ntile = MT + (((cur ^ 1) * 2 + wv) * 1024);
#pragma unroll
            for (int j = 0; j < 4; j++)
                gload16(msrcJ[j] + tt + 64, ntile + j * 256);
        }
        // 2. kmask + K register loads (L2)
        f32x4 km[4];
        bf16x8 aK[4][2];
#pragma unroll
        for (int c = 0; c < 4; c++) {
            km[c] = *(const f32x4*)(kmb + tt + 16 * c);
            const bf16* kp = kbase + (size_t)(tt + 16 * c) * HDIM;
            aK[c][0] = *(const bf16x8*)kp;
            aK[c][1] = *(const bf16x8*)(kp + 32);
        }
        // 3. QK^T (swapped): sc[c][r] = score(q=l15, k=kk_base+tt+16c+4g+r)
        f32x4 sc[4];
#pragma unroll
        for (int c = 0; c < 4; c++) {
            f32x4 s = zero4;
            s = __builtin_amdgcn_mfma_f32_16x16x32_bf16(aK[c][0], bQ0, s, 0, 0, 0);
            s = __builtin_amdgcn_mfma_f32_16x16x32_bf16(aK[c][1], bQ1, s, 0, 0, 0);
            sc[c] = s;
        }
        // 4. V loads (L2), consumed after softmax
        bf16x8 bV[4][2];
#pragma unroll
        for (int dt = 0; dt < 4; dt++) {
            const bf16* vp = vbase + (size_t)(dt * 16) * S_LEN + tt;
            bV[dt][0] = *(const bf16x8*)vp;
            bV[dt][1] = *(const bf16x8*)(vp + 32);
        }
        // 5. mask add from LDS tile (swizzled) + kmask regs
#pragma unroll
        for (int c = 0; c < 4; c++) {
            int phys = (4 * c + g) ^ (l15 & 7);
            f32x4 mk = *(const f32x4*)&tile[l15 * 64 + phys * 4];
            sc[c] += mk + km[c];
        }
        // 6. online softmax (rows q=l15 live per-lane)
        float cm = fmaxf(fmaxf(fmaxf(sc[0][0], sc[0][1]), fmaxf(sc[0][2], sc[0][3])),
                         fmaxf(fmaxf(sc[1][0], sc[1][1]), fmaxf(sc[1][2], sc[1][3])));
        cm = fmaxf(cm, fmaxf(fmaxf(fmaxf(sc[2][0], sc[2][1]), fmaxf(sc[2][2], sc[2][3])),
                             fmaxf(fmaxf(sc[3][0], sc[3][1]), fmaxf(sc[3][2], sc[3][3]))));
        cm = fmaxf(cm, __shfl_xor(cm, 16, 64));
        cm = fmaxf(cm, __shfl_xor(cm, 32, 64));
        if (!__all(cm - mrun <= 8.0f)) {             // defer-max (T13)
            float mn = fmaxf(mrun, cm);
            float f = __expf(mrun - mn);
            mrun = mn;
            lrun *= f;
#pragma unroll
            for (int r = 0; r < 4; r++) {
                float fb = __shfl(f, 4 * g + r, 64);
#pragma unroll
                for (int dt = 0; dt < 4; dt++) O[dt][r] *= fb;
            }
        }
        float rs = 0.f;
#pragma unroll
        for (int c = 0; c < 4; c++)
#pragma unroll
            for (int r = 0; r < 4; r++) {
                float p = __expf(sc[c][r] - mrun);
                sc[c][r] = p;
                rs += p;
            }
        rs += __shfl_xor(rs, 16, 64);
        rs += __shfl_xor(rs, 32, 64);
        lrun += rs;
        // 7. P -> per-wave LDS roundtrip (rule-18 fence)
#pragma unroll
        for (int c = 0; c < 4; c++) {
            bf16x4 pk;
            pk[0] = (bf16)sc[c][0]; pk[1] = (bf16)sc[c][1];
            pk[2] = (bf16)sc[c][2]; pk[3] = (bf16)sc[c][3];
            *(bf16x4*)&P[wv][l15][16 * c + 4 * g] = pk;
        }
        asm volatile("s_waitcnt lgkmcnt(0)" ::: "memory");
        __builtin_amdgcn_sched_barrier(0);
        bf16x8 aP0 = *(const bf16x8*)&P[wv][l15][g * 8];
        bf16x8 aP1 = *(const bf16x8*)&P[wv][l15][32 + g * 8];
        // 8. PV
#pragma unroll
        for (int dt = 0; dt < 4; dt++) {
            O[dt] = __builtin_amdgcn_mfma_f32_16x16x32_bf16(aP0, bV[dt][0], O[dt], 0, 0, 0);
            O[dt] = __builtin_amdgcn_mfma_f32_16x16x32_bf16(aP1, bV[dt][1], O[dt], 0, 0, 0);
        }
        __syncthreads();   // drains next-tile DMA; aligns waves
    }

    // ---- split-K merge: h=1 publishes, h=0 merges and writes ctx ----
    float* MG = (float*)SMEM;                        // reuse mask region (9.4 KB)
    float* ob = MG + b * 1152;                       // [64 lanes][17]
    float* ml = MG + 2304 + b * 40;                  // m[16], l[16]
    if (h == 1) {
#pragma unroll
        for (int t = 0; t < 4; t++)
#pragma unroll
            for (int r = 0; r < 4; r++)
                ob[lane * 17 + t * 4 + r] = O[t][r];
        if (g == 0) { ml[l15] = mrun; ml[16 + l15] = lrun; }
    }
    __syncthreads();
    if (h == 0) {
        float m1 = ml[l15], l1 = ml[16 + l15];
        float mstar = fmaxf(mrun, m1);
        float f0 = __expf(mrun - mstar), f1 = __expf(m1 - mstar);
        float lstar = lrun * f0 + l1 * f1;
#pragma unroll
        for (int r = 0; r < 4; r++) {
            float fq0 = __shfl(f0, 4 * g + r, 64);
            float fq1 = __shfl(f1, 4 * g + r, 64);
            float lq  = __shfl(lstar, 4 * g + r, 64);
            float inv = 1.0f / lq;
            int s = q0 + 4 * g + r;
            int token = s * BATCH + b;
#pragma unroll
            for (int dt = 0; dt < 4; dt++) {
                float o1 = ob[lane * 17 + dt * 4 + r];
                float om = O[dt][r] * fq0 + o1 * fq1;
                int hh = nh * HDIM + dt * 16 + l15;
                ctx[(size_t)token * HID + hh] = (bf16)(om * inv);
            }
        }
    }
}

extern "C" void kernel_launch(void* const* d_in, const int* in_sizes, int n_in,
                              void* d_out, int out_size, void* d_ws, size_t ws_size,
                              hipStream_t stream) {
    const float* hidden = (const float*)d_in[0];
    const float* amask  = (const float*)d_in[1];
    const float* kmask  = (const float*)d_in[2];
    const float* Wq = (const float*)d_in[3];
    const float* bq = (const float*)d_in[4];
    const float* Wk = (const float*)d_in[5];
    const float* bk = (const float*)d_in[6];
    const float* Wv = (const float*)d_in[7];
    const float* bv = (const float*)d_in[8];
    const float* Wo = (const float*)d_in[9];
    const float* bo = (const float*)d_in[10];
    float* out = (float*)d_out;

    char* ws = (char*)d_ws;
    bf16* Xb   = (bf16*)(ws);                       // 8 MB  [4096][1024]
    bf16* Wcat = (bf16*)(ws + (8u  << 20));         // 6 MB  [3072][1024]
    bf16* Wob  = (bf16*)(ws + (14u << 20));         // 2 MB  [1024][1024]
    bf16* qh   = (bf16*)(ws + (16u << 20));         // 8 MB  [32][2048][64]
    bf16* kh   = (bf16*)(ws + (24u << 20));         // 8 MB
    bf16* vT   = (bf16*)(ws + (40u << 20));         // 8 MB  [32][64][2048]
    bf16* ctx  = (bf16*)(ws + (48u << 20));         // 8 MB  [4096][1024]

    cvt_f32_bf16<<<2048, 256, 0, stream>>>(hidden, Xb, NTOK * HID);
    cvt_f32_bf16<<<512, 256, 0, stream>>>(Wq, Wcat,              HID * HID);
    cvt_f32_bf16<<<512, 256, 0, stream>>>(Wk, Wcat + HID * HID,  HID * HID);
    cvt_f32_bf16<<<512, 256, 0, stream>>>(Wv, Wcat + 2 * HID * HID, HID * HID);
    cvt_f32_bf16<<<512, 256, 0, stream>>>(Wo, Wob, HID * HID);

    gemm_bt<<<dim3(24, 32), 256, 0, stream>>>(Xb, Wcat, NTOK, 3 * HID, HID, 0,
                                              bq, bk, bv, bo, qh, kh, vT, nullptr);
    attn<<<dim3(128, 16), 256, 0, stream>>>(qh, kh, vT, amask, kmask, ctx);
    gemm_bt<<<dim3(8, 32), 256, 0, stream>>>(ctx, Wob, NTOK, HID, HID, 1,
                                             bq, bk, bv, bo, qh, kh, vT, out);
}